// Round 2
// baseline (3089.967 us; speedup 1.0000x reference)
//
#include <hip/hip_runtime.h>
#include <math.h>

#define NN 1024
#define BB 32
#define TT 12
#define HH 64
#define K1 65
#define NCOLS (BB * K1)   // 2080 valid columns
#define NC2 2176          // padded to 17*128
#define NH (NN * HH)      // 65536
#define KP 2048           // physical K (hi | lo)
#define KGEMM 3072        // gemm K: hiA*hiX | loA*hiX | hiA*loX
#define BM 128
#define BN 128
#define BKK 64

typedef unsigned short u16;
typedef __attribute__((ext_vector_type(8))) short bh8;
typedef __attribute__((ext_vector_type(4))) float f32x4;

__device__ __forceinline__ u16 f2bf(float x) {
    union { float f; unsigned u; } v; v.f = x;
    unsigned r = v.u + 0x7FFFu + ((v.u >> 16) & 1u);
    return (u16)(r >> 16);
}
__device__ __forceinline__ float bf2f(u16 u) {
    union { unsigned u; float f; } v; v.u = ((unsigned)u) << 16;
    return v.f;
}
__device__ __forceinline__ void gload16(const void* g, void* l) {
    __builtin_amdgcn_global_load_lds((__attribute__((address_space(1))) void*)g,
                                     (__attribute__((address_space(3))) void*)l,
                                     16, 0, 0);
}

// ---------------- row-sum -> d^{-1/2} ----------------
__global__ void rowsum_rsqrt(const float* __restrict__ M, float* __restrict__ ds) {
    int row = blockIdx.x;
    const float* p = M + (size_t)row * NN;
    float s = 0.f;
    for (int i = threadIdx.x; i < NN; i += blockDim.x) s += p[i];
    __shared__ float red[256];
    red[threadIdx.x] = s;
    __syncthreads();
    for (int off = 128; off; off >>= 1) {
        if (threadIdx.x < off) red[threadIdx.x] += red[threadIdx.x + off];
        __syncthreads();
    }
    if (threadIdx.x == 0) {
        float d = red[0];
        ds[row] = d > 0.f ? 1.0f / sqrtf(d) : 0.f;
    }
}

// ---------------- build A_t in split bf16: A2[t][m][0:1024]=hi, [1024:2048]=lo ----
__global__ void build_A2(const float* __restrict__ dtw, const float* __restrict__ adj,
                         const float* __restrict__ spec, const float* __restrict__ td,
                         const float* __restrict__ dsA, const float* __restrict__ dsS,
                         const int* __restrict__ sr_ptr, u16* __restrict__ A2) {
    int idx = blockIdx.x * blockDim.x + threadIdx.x;
    int m = idx >> 10, n = idx & 1023;
    float sr = (float)sr_ptr[0];
    float dtw_v = dtw[idx], adj_v = adj[idx], spec_v = spec[idx], td_v = td[idx];
    float I = (m == n) ? 1.f : 0.f;
    float Lspec = I - dsS[m] * spec_v * dsS[n];
    float Ladj  = I - dsA[m] * adj_v * dsA[n];
    float tind = (float)TT - ceilf(fabsf(td_v) / sr);
    float base2 = 0.5f * (Lspec + I);
    float base3 = (Lspec + Ladj + I) * (1.f / 3.f);
    bool nz = (dtw_v != 0.f);
#pragma unroll
    for (int t = 0; t < TT; ++t) {
        bool act = nz && ((float)(t + 1) > tind);
        float a = (t == TT - 1) ? base3 + (act ? dtw_v * (1.f / 3.f) : 0.f)
                                : base2 + (act ? dtw_v * 0.5f : 0.f);
        u16 hi = f2bf(a);
        u16 lo = f2bf(a - bf2f(hi));
        size_t rowb = ((size_t)t * NN + m) * KP;
        A2[rowb + n] = hi;
        A2[rowb + 1024 + n] = lo;
    }
}

// ---------------- build cat (transposed, split): cat[z][col][k'], k'<1024 hi, else lo ----
// pass2: value = sigmoid(gcn1)*h instead of h (for feature cols)
__global__ __launch_bounds__(256) void build_cat(
    const float* __restrict__ inputs, const float* __restrict__ states,
    const u16* __restrict__ rall, const float* __restrict__ cum1,
    u16* __restrict__ cat, int tbase, int pass2) {
    __shared__ float hs[64][68];
    __shared__ float rs[64][68];
    const int z = blockIdx.z, t = tbase + z;
    const int b = blockIdx.y, nb = blockIdx.x;
    const int tid = threadIdx.x;
    const float* sb = states + ((size_t)t * BB + b) * NH + (size_t)nb * 4096;
    {
        const float4* src = (const float4*)sb;
#pragma unroll
        for (int q = 0; q < 4; ++q) {
            float4 v = src[tid * 4 + q];
            int fi = tid * 16 + q * 4;
            *(float4*)&hs[fi >> 6][fi & 63] = v;
        }
        if (pass2) {
            if (rall) {
                const u16* rb = rall + ((size_t)t * BB + b) * NH + (size_t)nb * 4096;
#pragma unroll
                for (int i = 0; i < 16; ++i) {
                    int fi = tid * 16 + i;
                    rs[fi >> 6][fi & 63] = bf2f(rb[fi]);
                }
            } else {
                const float* cb = cum1 + (size_t)b * (2 * NH) + (size_t)nb * 4096;
#pragma unroll
                for (int i = 0; i < 16; ++i) {
                    int fi = tid * 16 + i;
                    float g = cb[fi];
                    rs[fi >> 6][fi & 63] = 1.f / (1.f + expf(-g));
                }
            }
        }
    }
    __syncthreads();
    u16* catz = cat + (size_t)z * NC2 * KP;
    // feature columns: col = b*65 + 1 + jp, handles nodes [nb*64+ni, +16)
    int jp = tid >> 2, ni = (tid & 3) << 4;
    int col = b * K1 + 1 + jp;
    u16 hib[16], lob[16];
#pragma unroll
    for (int i = 0; i < 16; ++i) {
        float v = hs[ni + i][jp];
        if (pass2) v *= rs[ni + i][jp];
        u16 hi = f2bf(v);
        hib[i] = hi;
        lob[i] = f2bf(v - bf2f(hi));
    }
    size_t dst = (size_t)col * KP + nb * 64 + ni;
    *(uint4*)(catz + dst)        = *(uint4*)&hib[0];
    *(uint4*)(catz + dst + 8)    = *(uint4*)&hib[8];
    *(uint4*)(catz + dst + 1024) = *(uint4*)&lob[0];
    *(uint4*)(catz + dst + 1032) = *(uint4*)&lob[8];
    // x column (col = b*65)
    if (tid < 64) {
        float v = inputs[((size_t)b * TT + t) * NN + nb * 64 + tid];
        u16 hi = f2bf(v);
        size_t xb = (size_t)(b * K1) * KP + nb * 64 + tid;
        catz[xb] = hi;
        catz[xb + 1024] = f2bf(v - bf2f(hi));
    }
}

// ---------------- MFMA GEMM: P[z][m][col] = sum_k A[m][k]*X[k][col], K=3072 split ----
__global__ __launch_bounds__(256) void gemm_bf16(
    const u16* __restrict__ A2, const u16* __restrict__ cat,
    float* __restrict__ P, int tbase) {
    __shared__ __align__(16) u16 As[2][BM * BKK];
    __shared__ __align__(16) u16 Xs[2][BN * BKK];
    const int tid = threadIdx.x;
    const int lane = tid & 63;
    const int wid = tid >> 6;
    const int z = blockIdx.z;
    const int m0 = blockIdx.y * BM;
    const int n0 = blockIdx.x * BN;
    const u16* Ab = A2 + (size_t)(tbase + z) * NN * KP + (size_t)m0 * KP;
    const u16* Xb = cat + (size_t)z * NC2 * KP + (size_t)n0 * KP;
    const int pm = tid & 127;   // row within tile for staging (invariant over c)

    f32x4 acc[4][4];
#pragma unroll
    for (int i = 0; i < 4; ++i)
#pragma unroll
        for (int j = 0; j < 4; ++j) acc[i][j] = {0.f, 0.f, 0.f, 0.f};

    const int wm = (wid >> 1) << 6;
    const int wn = (wid & 1) << 6;
    const int fl = lane & 15;
    const int fh = lane >> 4;

    auto stage = [&](int buf, int k0) {
        int pA = (k0 < KP) ? k0 : k0 - KP;
        int pX = (k0 < NN) ? k0 : k0 - NN;
#pragma unroll
        for (int c = 0; c < 4; ++c) {
            int p = c * 256 + tid;
            int kg = p >> 7;   // 0..7
            gload16(Ab + (size_t)pm * KP + pA + kg * 8, &As[buf][(size_t)p * 8]);
            gload16(Xb + (size_t)pm * KP + pX + kg * 8, &Xs[buf][(size_t)p * 8]);
        }
    };
    auto compute = [&](int buf) {
#pragma unroll
        for (int ks = 0; ks < 2; ++ks) {
            bh8 a[4], x[4];
            int kgb = (ks << 2) + fh;
#pragma unroll
            for (int i = 0; i < 4; ++i) {
                a[i] = *(const bh8*)&As[buf][(size_t)((kgb << 7) + wm + (i << 4) + fl) * 8];
                x[i] = *(const bh8*)&Xs[buf][(size_t)((kgb << 7) + wn + (i << 4) + fl) * 8];
            }
#pragma unroll
            for (int i = 0; i < 4; ++i)
#pragma unroll
                for (int j = 0; j < 4; ++j)
                    acc[i][j] = __builtin_amdgcn_mfma_f32_16x16x32_bf16(a[i], x[j], acc[i][j], 0, 0, 0);
        }
    };

    stage(0, 0);
    __syncthreads();
    const int nk = KGEMM / BKK;   // 48
#pragma unroll 2
    for (int it = 0; it < nk; ++it) {
        int cur = it & 1;
        if (it + 1 < nk) stage(cur ^ 1, (it + 1) * BKK);
        compute(cur);
        __syncthreads();
    }
    float* Pz = P + (size_t)z * NN * NC2;
#pragma unroll
    for (int i = 0; i < 4; ++i) {
        int row0 = m0 + wm + (i << 4) + (fh << 2);
#pragma unroll
        for (int j = 0; j < 4; ++j) {
            int col = n0 + wn + (j << 4) + fl;
#pragma unroll
            for (int r = 0; r < 4; ++r)
                Pz[(size_t)(row0 + r) * NC2 + col] = acc[i][j][r];
        }
    }
}

// ---------------- stage2: cum[b][m*KOUT+k2] += P[m][b*65+k] W[k][k2] + bias ----
template <int KOUT, int NTHR>
__global__ __launch_bounds__(NTHR) void stage2(const float* __restrict__ P,
                                               const float* __restrict__ W,
                                               const float* __restrict__ bias,
                                               float* __restrict__ cum,
                                               u16* __restrict__ rall, int t) {
    __shared__ float Pl[K1][36];
    __shared__ float Wl[K1 * KOUT];
    int m = blockIdx.x;
    for (int i = threadIdx.x; i < NCOLS; i += NTHR) {
        int b = i / K1, k = i - b * K1;
        Pl[k][b] = P[(size_t)m * NC2 + i];
    }
    for (int i = threadIdx.x; i < K1 * KOUT; i += NTHR) Wl[i] = W[i];
    __syncthreads();

    int k2q = (threadIdx.x % (KOUT / 4)) << 2;
    int bq  = (threadIdx.x / (KOUT / 4)) << 2;
    float acc[4][4] = {};
#pragma unroll
    for (int k = 0; k < K1; ++k) {
        float4 p4 = *(const float4*)&Pl[k][bq];
        float4 w4 = *(const float4*)&Wl[k * KOUT + k2q];
        const float pr[4] = {p4.x, p4.y, p4.z, p4.w};
        const float wr[4] = {w4.x, w4.y, w4.z, w4.w};
#pragma unroll
        for (int i = 0; i < 4; ++i)
#pragma unroll
            for (int j = 0; j < 4; ++j) acc[i][j] += pr[i] * wr[j];
    }
    const float4 bv = *(const float4*)(bias + k2q);
    const float brr[4] = {bv.x, bv.y, bv.z, bv.w};
#pragma unroll
    for (int i = 0; i < 4; ++i) {
        int b = bq + i;
        float* cp = cum + (size_t)b * NN * KOUT + (size_t)m * KOUT + k2q;
        float4 g = *(float4*)cp;
        float nv[4] = {g.x + acc[i][0] + brr[0], g.y + acc[i][1] + brr[1],
                       g.z + acc[i][2] + brr[2], g.w + acc[i][3] + brr[3]};
        g.x = nv[0]; g.y = nv[1]; g.z = nv[2]; g.w = nv[3];
        *(float4*)cp = g;
        if (KOUT == 128 && rall != nullptr && m < 512) {
#pragma unroll
            for (int j = 0; j < 4; ++j) {
                float s = 1.f / (1.f + expf(-nv[j]));
                rall[((size_t)t * BB + b) * NH + (size_t)m * 128 + k2q + j] = f2bf(s);
            }
        }
    }
}

// ---------------- finalize ----------------
__global__ void finalize(const float* __restrict__ cum1, const float* __restrict__ cum2,
                         const float* __restrict__ states, float* __restrict__ out) {
    int idx = blockIdx.x * blockDim.x + threadIdx.x;
    if (idx >= BB * NH) return;
    int b = idx >> 16;
    int f = idx & (NH - 1);
    float u = 1.f / (1.f + expf(-cum1[(size_t)b * 2 * NH + NH + f]));
    float h = states[((size_t)(TT - 1) * BB + b) * NH + f];
    float c = tanhf(cum2[idx]);
    float o = u * h + (1.f - u) * c;
    out[idx] = o;
    out[(size_t)BB * NH + idx] = o;
}

extern "C" void kernel_launch(void* const* d_in, const int* in_sizes, int n_in,
                              void* d_out, int out_size, void* d_ws, size_t ws_size,
                              hipStream_t stream) {
    const float* inputs = (const float*)d_in[0];
    const float* states = (const float*)d_in[1];
    const float* dtw    = (const float*)d_in[2];
    const float* adj    = (const float*)d_in[3];
    const float* spec   = (const float*)d_in[4];
    const float* td     = (const float*)d_in[5];
    const float* W1     = (const float*)d_in[6];
    const float* b1     = (const float*)d_in[7];
    const float* W2     = (const float*)d_in[8];
    const float* b2     = (const float*)d_in[9];
    const int*   sr     = (const int*)d_in[10];
    float* out = (float*)d_out;

    char* ws = (char*)d_ws;
    const size_t szA2   = (size_t)TT * NN * KP * 2;         // 50331648
    const size_t szCum1 = (size_t)BB * 2 * NH * 4;          // 16777216
    const size_t szCum2 = (size_t)BB * NH * 4;              // 8388608
    const size_t szRall = (size_t)TT * BB * NH * 2;         // 50331648
    const size_t szCat1 = (size_t)NC2 * KP * 2;             // 8912896 per t
    const size_t szP1   = (size_t)NN * NC2 * 4;             // 8912896 per t

    u16*   A2   = (u16*)ws;
    float* cum1 = (float*)(ws + szA2);
    float* cum2 = (float*)(ws + szA2 + szCum1);
    float* dsA  = (float*)(ws + szA2 + szCum1 + szCum2);
    float* dsS  = (float*)(ws + szA2 + szCum1 + szCum2 + 4096);
    size_t offRest = szA2 + szCum1 + szCum2 + 8192;

    const size_t needBatched = offRest + szRall + 4 * (szCat1 + szP1);
    bool batched = (ws_size >= needBatched);

    rowsum_rsqrt<<<NN, 256, 0, stream>>>(adj, dsA);
    rowsum_rsqrt<<<NN, 256, 0, stream>>>(spec, dsS);
    build_A2<<<(NN * NN) / 256, 256, 0, stream>>>(dtw, adj, spec, td, dsA, dsS, sr, A2);
    hipMemsetAsync(cum1, 0, szCum1, stream);
    hipMemsetAsync(cum2, 0, szCum2, stream);

    if (batched) {
        const int C = 4;
        u16*   rall = (u16*)(ws + offRest);
        u16*   cat  = (u16*)(ws + offRest + szRall);
        float* P    = (float*)(ws + offRest + szRall + C * szCat1);
        // pass 1 (batched chunks) + sequential prefix via stage2
        for (int tb = 0; tb < TT; tb += C) {
            build_cat<<<dim3(16, 32, C), 256, 0, stream>>>(inputs, states, nullptr, nullptr, cat, tb, 0);
            gemm_bf16<<<dim3(NC2 / BN, NN / BM, C), 256, 0, stream>>>(A2, cat, P, tb);
            for (int z = 0; z < C; ++z)
                stage2<128, 256><<<NN, 256, 0, stream>>>(P + (size_t)z * NN * NC2, W1, b1, cum1, rall, tb + z);
        }
        // pass 2 (batched chunks)
        for (int tb = 0; tb < TT; tb += C) {
            build_cat<<<dim3(16, 32, C), 256, 0, stream>>>(inputs, states, rall, nullptr, cat, tb, 1);
            gemm_bf16<<<dim3(NC2 / BN, NN / BM, C), 256, 0, stream>>>(A2, cat, P, tb);
            for (int z = 0; z < C; ++z)
                stage2<64, 128><<<NN, 128, 0, stream>>>(P + (size_t)z * NN * NC2, W2, b2, cum2, nullptr, 0);
        }
    } else {
        u16*   cat = (u16*)(ws + offRest);
        float* P   = (float*)(ws + offRest + szCat1);
        for (int t = 0; t < TT; ++t) {
            build_cat<<<dim3(16, 32, 1), 256, 0, stream>>>(inputs, states, nullptr, nullptr, cat, t, 0);
            gemm_bf16<<<dim3(NC2 / BN, NN / BM, 1), 256, 0, stream>>>(A2, cat, P, t);
            stage2<128, 256><<<NN, 256, 0, stream>>>(P, W1, b1, cum1, nullptr, 0);
            build_cat<<<dim3(16, 32, 1), 256, 0, stream>>>(inputs, states, nullptr, cum1, cat, t, 1);
            gemm_bf16<<<dim3(NC2 / BN, NN / BM, 1), 256, 0, stream>>>(A2, cat, P, t);
            stage2<64, 128><<<NN, 128, 0, stream>>>(P, W2, b2, cum2, nullptr, 0);
        }
    }
    finalize<<<(BB * NH + 255) / 256, 256, 0, stream>>>(cum1, cum2, states, out);
}